// Round 4
// baseline (1110.013 us; speedup 1.0000x reference)
//
#include <hip/hip_runtime.h>
#include <stdint.h>

#define B_ 1024
#define N_ 224
#define TS 112
#define KB 16

// async global -> LDS, 16B per lane (guide: compiler never auto-emits this)
__device__ __forceinline__ void gload16(const void* g, void* l) {
  __builtin_amdgcn_global_load_lds(
      (const __attribute__((address_space(1))) uint32_t*)g,
      (__attribute__((address_space(3))) uint32_t*)l,
      16, 0, 0);
}

// Batched C = A @ B, all matrices 224x224 fp32 row-major, grid (2,2,batch).
// 112x112 output tile per block, 256 threads (16x16), 7x7 micro-tile, BK=16.
__global__ __launch_bounds__(256) void gemm224(const float* __restrict__ Ag,
                                               const float* __restrict__ Bg,
                                               float* __restrict__ Cg) {
  // LDS double buffers: As [112][16] row-major (m*16+k), Bs [16][112] (k*112+n).
  // Both are linear in the global_load_lds lane order (base + lane*16).
  __shared__ __align__(16) float As[2][TS * KB];
  __shared__ __align__(16) float Bs[2][KB * TS];

  const size_t mo = (size_t)blockIdx.z * (N_ * N_);
  const float* A = Ag + mo;
  const float* Bm = Bg + mo;
  float* C = Cg + mo;
  const int m0 = blockIdx.x * TS;
  const int n0 = blockIdx.y * TS;
  const int t = threadIdx.x;
  const int tx = t & 15, ty = t >> 4;

  // Loop-invariant staging offsets (hoisted so the K-loop staging is add-only).
  // A tile: 448 float4s, f -> row f/4, col4 (f%4)*4.  addr = A + aOff + k0
  // B tile: 448 float4s, f -> row f/28, col4 (f%28)*4. addr = Bm + bOff + k0*N_
  const int f1 = t + 256;                         // second chunk (t<192 active; wave-uniform predicate)
  const size_t aOff0 = (size_t)(m0 + (t >> 2)) * N_ + ((t & 3) << 2);
  const size_t bOff0 = (size_t)(t / 28) * N_ + n0 + (t % 28) * 4;
  const size_t aOff1 = (size_t)(m0 + (f1 >> 2)) * N_ + ((f1 & 3) << 2);
  const size_t bOff1 = (size_t)(f1 / 28) * N_ + n0 + (f1 % 28) * 4;
  const int l0 = t << 2;                          // LDS float index = f*4
  const int l1 = f1 << 2;

  float acc[7][7] = {};

  auto stage = [&](int buf, int k0) {
    gload16(A + aOff0 + k0, &As[buf][l0]);
    gload16(Bm + bOff0 + (size_t)k0 * N_, &Bs[buf][l0]);
    if (f1 < 448) {
      gload16(A + aOff1 + k0, &As[buf][l1]);
      gload16(Bm + bOff1 + (size_t)k0 * N_, &Bs[buf][l1]);
    }
  };

  stage(0, 0);
  int cur = 0;
  for (int kt = 0; kt < N_ / KB; ++kt) {
    // top barrier: (a) drains vmcnt -> buf[cur] staged data ready,
    // (b) all threads done reading buf[cur^1] from last iter -> safe to overwrite.
    __syncthreads();
    if (kt + 1 < N_ / KB) stage(cur ^ 1, (kt + 1) * KB);  // fly under the FMAs
    const float* Asb = As[cur];
    const float* Bsb = Bs[cur];
#pragma unroll
    for (int k = 0; k < KB; ++k) {
      float a[7], bv[7];
#pragma unroll
      for (int i = 0; i < 7; ++i) a[i] = Asb[(ty + (i << 4)) * KB + k];  // 2-way bank alias -> free (m136)
#pragma unroll
      for (int j = 0; j < 7; ++j) bv[j] = Bsb[k * TS + tx + (j << 4)];  // 16-addr broadcast -> conflict-free
#pragma unroll
      for (int i = 0; i < 7; ++i)
#pragma unroll
        for (int j = 0; j < 7; ++j) acc[i][j] = fmaf(a[i], bv[j], acc[i][j]);
    }
    cur ^= 1;
  }

#pragma unroll
  for (int i = 0; i < 7; ++i) {
    float* crow = C + (size_t)(m0 + ty + (i << 4)) * N_ + n0 + tx;
#pragma unroll
    for (int j = 0; j < 7; ++j) crow[j << 4] = acc[i][j];
  }
}

// Per batch: d2=diag(P2), d3=diag(P3), d4[n]=sum_k P2[n,k]P2[k,n], d5[n]=sum_k P3[n,k]P2[k,n].
// One block per matrix; thread t owns n=t. Rows staged via LDS slabs (pad +1 -> 2-way max,
// free per m136); columns read coalesced (thread n -> consecutive addresses).
__global__ __launch_bounds__(256) void diagk(const float* __restrict__ P2g,
                                             const float* __restrict__ P3g,
                                             float* __restrict__ dg, int bBase) {
  __shared__ float s2[N_][KB + 1];
  __shared__ float s3[N_][KB + 1];
  const int b = blockIdx.x;
  const float* p2 = P2g + (size_t)b * N_ * N_;
  const float* p3 = P3g + (size_t)b * N_ * N_;
  const int gb = bBase + b;
  const int t = threadIdx.x;
  float d4 = 0.f, d5 = 0.f;
  for (int kb = 0; kb < N_; kb += KB) {
    __syncthreads();
#pragma unroll
    for (int base = 0; base < N_ * KB; base += 256) {  // 3584 = 14*256 exact
      int f = base + t;
      int n = f >> 4, j = f & 15;
      s2[n][j] = p2[(size_t)n * N_ + kb + j];
      s3[n][j] = p3[(size_t)n * N_ + kb + j];
    }
    __syncthreads();
    if (t < N_) {
#pragma unroll
      for (int j = 0; j < KB; ++j) {
        float c2 = p2[(size_t)(kb + j) * N_ + t];  // column, coalesced across threads
        d4 = fmaf(s2[t][j], c2, d4);
        d5 = fmaf(s3[t][j], c2, d5);
      }
    }
  }
  if (t < N_) {
    dg[((size_t)0 * B_ + gb) * N_ + t] = p2[(size_t)t * N_ + t];
    dg[((size_t)1 * B_ + gb) * N_ + t] = p3[(size_t)t * N_ + t];
    dg[((size_t)2 * B_ + gb) * N_ + t] = d4;
    dg[((size_t)3 * B_ + gb) * N_ + t] = d5;
  }
}

// One wave per batch: T[i][j] = sum_n d_i[n]^(j+1); out = sum coef*T/ (N*N)^(i+j+2).
__global__ __launch_bounds__(256) void combine(const float* __restrict__ dg,
                                               const float* __restrict__ coef,
                                               float* __restrict__ out) {
  const int lane = threadIdx.x & 63;
  const int b = blockIdx.x * 4 + (threadIdx.x >> 6);
  float T[4][4] = {};
  for (int n = lane; n < N_; n += 64) {
#pragma unroll
    for (int i = 0; i < 4; ++i) {
      float d = dg[((size_t)i * B_ + b) * N_ + n];
      float p = d;
#pragma unroll
      for (int j = 0; j < 4; ++j) {
        T[i][j] += p;
        p *= d;
      }
    }
  }
#pragma unroll
  for (int i = 0; i < 4; ++i)
#pragma unroll
    for (int j = 0; j < 4; ++j)
#pragma unroll
      for (int s = 32; s > 0; s >>= 1) T[i][j] += __shfl_xor(T[i][j], s, 64);
  if (lane == 0) {
    double acc = 0.0;
#pragma unroll
    for (int i = 0; i < 4; ++i)
#pragma unroll
      for (int j = 0; j < 4; ++j) {
        double norm = 1.0;
        for (int e = 0; e < i + j + 2; ++e) norm *= (double)(N_ * N_);
        acc += (double)coef[i * 4 + j] * ((double)T[i][j] / norm);
      }
    out[b] = (float)acc;
  }
}

extern "C" void kernel_launch(void* const* d_in, const int* in_sizes, int n_in,
                              void* d_out, int out_size, void* d_ws, size_t ws_size,
                              hipStream_t stream) {
  (void)in_sizes; (void)n_in; (void)out_size;
  const float* x = (const float*)d_in[0];
  const float* coef = (const float*)d_in[1];
  float* out = (float*)d_out;
  char* ws = (char*)d_ws;

  // ws layout: [diag 4*B*N floats][P2 chunk][P3 chunk]; chunk batch to fit ws_size.
  const size_t diagBytes = (size_t)4 * B_ * N_ * sizeof(float);  // 3,670,016 (256-aligned)
  float* dg = (float*)ws;
  const size_t perMat = (size_t)N_ * N_ * sizeof(float);
  size_t rem = (ws_size > diagBytes + 256) ? (ws_size - diagBytes - 256) : 0;
  long long Cc = (long long)(rem / (2 * perMat));
  if (Cc < 1) Cc = 1;
  if (Cc > B_) Cc = B_;
  const int C = (int)Cc;
  float* P2 = (float*)(ws + ((diagBytes + 255) & ~(size_t)255));
  float* P3 = P2 + (size_t)C * N_ * N_;

  for (int b0 = 0; b0 < B_; b0 += C) {
    const int cb = (B_ - b0 < C) ? (B_ - b0) : C;
    const float* xc = x + (size_t)b0 * N_ * N_;
    dim3 g(2, 2, cb);
    gemm224<<<g, 256, 0, stream>>>(xc, xc, P2);   // P2 = x^2
    gemm224<<<g, 256, 0, stream>>>(P2, xc, P3);   // P3 = x^3
    diagk<<<cb, 256, 0, stream>>>(P2, P3, dg, b0);
  }
  combine<<<256, 256, 0, stream>>>(dg, coef, out);
}